// Round 3
// baseline (95.154 us; speedup 1.0000x reference)
//
#include <hip/hip_runtime.h>

#define B_SZ  128
#define CH    64
#define T_LEN 4096
#define HID   32
#define INS   3
#define TB    256   // t-columns per block

// ---------------------------------------------------------------------------
// Kernel 1: hypernetwork MLPs. One block per batch sample.
// Writes weight TRANSPOSED as wT[b][i][o] so kernel 2 reads per-i rows of
// consecutive outputs as float4s (wave-uniform -> scalar loads).
// ---------------------------------------------------------------------------
__global__ __launch_bounds__(256) void hyper_mlp_kernel(
    const float* __restrict__ z,
    const float* __restrict__ w_w1, const float* __restrict__ w_b1,
    const float* __restrict__ w_g,  const float* __restrict__ w_beta,
    const float* __restrict__ w_w2, const float* __restrict__ w_b2,
    const float* __restrict__ b_w1, const float* __restrict__ b_b1,
    const float* __restrict__ b_g,  const float* __restrict__ b_beta,
    const float* __restrict__ b_w2, const float* __restrict__ b_b2,
    float* __restrict__ wT,    // [B][CH_in][CH_out]
    float* __restrict__ bias)  // [B][CH]
{
  const int b   = blockIdx.x;
  const int tid = threadIdx.x;

  __shared__ float zs[INS];
  __shared__ float hraw[2][HID];
  __shared__ float hn[2][HID];

  if (tid < INS) zs[tid] = z[b * INS + tid];
  __syncthreads();

  if (tid < 2 * HID) {
    const int grp = tid >> 5;          // 0 = weight-MLP, 1 = bias-MLP
    const int j   = tid & 31;
    const float* w1 = grp ? b_w1 : w_w1;
    const float* b1 = grp ? b_b1 : w_b1;
    hraw[grp][j] = w1[j*3+0]*zs[0] + w1[j*3+1]*zs[1] + w1[j*3+2]*zs[2] + b1[j];
  }
  __syncthreads();

  if (tid < 2 * HID) {
    const int grp = tid >> 5;
    const int j   = tid & 31;
    float mu = 0.f;
    #pragma unroll
    for (int k = 0; k < HID; ++k) mu += hraw[grp][k];
    mu *= (1.0f / HID);
    float var = 0.f;
    #pragma unroll
    for (int k = 0; k < HID; ++k) { float d = hraw[grp][k] - mu; var += d * d; }
    var *= (1.0f / HID);
    const float r  = rsqrtf(var + 1e-5f);
    const float* g  = grp ? b_g    : w_g;
    const float* be = grp ? b_beta : w_beta;
    const float v = (hraw[grp][j] - mu) * r * g[j] + be[j];
    hn[grp][j] = fmaxf(v, 0.f);
  }
  __syncthreads();

  for (int m = tid; m < CH * CH; m += 256) {
    const float* row = w_w2 + m * HID;
    float acc = w_b2[m];
    #pragma unroll
    for (int i = 0; i < HID; ++i) acc += hn[0][i] * row[i];
    // m = o*64 + i  ->  wT[b][i][o]
    wT[(size_t)b * CH * CH + (m & 63) * CH + (m >> 6)] = acc;
  }

  if (tid < CH) {
    const float* row = b_w2 + tid * HID;
    float acc = b_b2[tid];
    #pragma unroll
    for (int i = 0; i < HID; ++i) acc += hn[1][i] * row[i];
    bias[b * CH + tid] = acc;
  }
}

// ---------------------------------------------------------------------------
// Kernel 2: per-batch 64x64 matrix applied to x[b][64][T].
// Block = 256 threads = 4 waves; one (b, 256-t tile). x tile [64][256] staged
// once in LDS (64 KB). Wave w owns 16 outputs o = 16w..16w+15 (weight address
// wave-uniform -> s_load). Lane owns 4 consecutive t. Per i-step per thread:
// 1 ds_read_b128 + 4 uniform 16B w-loads + 64 v_fmac -> 0.25 LDS B/FMA
// (4x less LDS traffic than round 2; LDS no longer co-saturated with VALU).
// acc[16] float4 = 64 VGPRs, all indices compile-time -> fully promoted.
// ---------------------------------------------------------------------------
__global__ __launch_bounds__(256, 2) void conv1x1_kernel(
    const float* __restrict__ x,
    const float* __restrict__ wT,
    const float* __restrict__ bias,
    float* __restrict__ out)
{
  const int b   = blockIdx.y;
  const int tbi = blockIdx.x;
  const int tid = threadIdx.x;

  __shared__ float4 xs[CH * (TB / 4)];   // [i][c] -> 64 KB

  // ---- stage x tile: 4096 float4s, 256 threads x 16, coalesced ----
  const float* xbase = x + (size_t)b * CH * T_LEN + tbi * TB;
  #pragma unroll
  for (int k = 0; k < 16; ++k) {
    const int f = tid + k * 256;
    const int i = f >> 6;          // row
    const int c = f & 63;          // float4 col
    xs[f] = *(const float4*)(xbase + (size_t)i * T_LEN + c * 4);
  }
  __syncthreads();

  const int lane = tid & 63;
  const int og   = __builtin_amdgcn_readfirstlane(tid >> 6);  // wave's o-group (16 outputs)

  const float4* wp = (const float4*)wT + (size_t)b * (CH * CH / 4) + og * 4;

  float4 acc[16];
  #pragma unroll
  for (int q = 0; q < 16; ++q) acc[q] = make_float4(0.f, 0.f, 0.f, 0.f);

  #pragma unroll 4
  for (int i = 0; i < CH; ++i) {
    const float4 xv = xs[i * 64 + lane];
    #pragma unroll
    for (int q = 0; q < 4; ++q) {
      const float4 wv = wp[i * 16 + q];   // w[i][og*16+4q .. +3], wave-uniform
      acc[q*4+0].x += wv.x * xv.x; acc[q*4+0].y += wv.x * xv.y;
      acc[q*4+0].z += wv.x * xv.z; acc[q*4+0].w += wv.x * xv.w;
      acc[q*4+1].x += wv.y * xv.x; acc[q*4+1].y += wv.y * xv.y;
      acc[q*4+1].z += wv.y * xv.z; acc[q*4+1].w += wv.y * xv.w;
      acc[q*4+2].x += wv.z * xv.x; acc[q*4+2].y += wv.z * xv.y;
      acc[q*4+2].z += wv.z * xv.z; acc[q*4+2].w += wv.z * xv.w;
      acc[q*4+3].x += wv.w * xv.x; acc[q*4+3].y += wv.w * xv.y;
      acc[q*4+3].z += wv.w * xv.z; acc[q*4+3].w += wv.w * xv.w;
    }
  }

  const float* bp = bias + b * CH + og * 16;
  float* op = out + ((size_t)b * CH + og * 16) * T_LEN + tbi * TB + lane * 4;

  #pragma unroll
  for (int m = 0; m < 16; ++m) {
    const float bb = bp[m];
    float4 r;
    r.x = acc[m].x + bb; r.y = acc[m].y + bb;
    r.z = acc[m].z + bb; r.w = acc[m].w + bb;
    *(float4*)(op + (size_t)m * T_LEN) = r;
  }
}

extern "C" void kernel_launch(void* const* d_in, const int* in_sizes, int n_in,
                              void* d_out, int out_size, void* d_ws, size_t ws_size,
                              hipStream_t stream) {
  const float* x      = (const float*)d_in[0];
  const float* z      = (const float*)d_in[1];
  const float* w_w1   = (const float*)d_in[2];
  const float* w_b1   = (const float*)d_in[3];
  const float* w_g    = (const float*)d_in[4];
  const float* w_beta = (const float*)d_in[5];
  const float* w_w2   = (const float*)d_in[6];
  const float* w_b2   = (const float*)d_in[7];
  const float* b_w1   = (const float*)d_in[8];
  const float* b_b1   = (const float*)d_in[9];
  const float* b_g    = (const float*)d_in[10];
  const float* b_beta = (const float*)d_in[11];
  const float* b_w2   = (const float*)d_in[12];
  const float* b_b2   = (const float*)d_in[13];

  float* out  = (float*)d_out;
  float* wT   = (float*)d_ws;                      // 128*64*64 floats = 2 MB
  float* bias = wT + (size_t)B_SZ * CH * CH;       // 128*64 floats

  hyper_mlp_kernel<<<B_SZ, 256, 0, stream>>>(
      z, w_w1, w_b1, w_g, w_beta, w_w2, w_b2,
      b_w1, b_b1, b_g, b_beta, b_w2, b_b2, wT, bias);

  dim3 grid(T_LEN / TB, B_SZ);
  conv1x1_kernel<<<grid, 256, 0, stream>>>(x, wT, bias, out);
}

// Round 4
// 90.646 us; speedup vs baseline: 1.0497x; 1.0497x over previous
//
#include <hip/hip_runtime.h>

#define B_SZ  128
#define CH    64
#define T_LEN 4096
#define HID   32
#define INS   3
#define TB    256   // t-columns per block

// ---------------------------------------------------------------------------
// Kernel 1: hypernetwork MLPs. One block per batch sample.
// Writes weight TRANSPOSED as wT[b][i][o].
// ---------------------------------------------------------------------------
__global__ __launch_bounds__(256) void hyper_mlp_kernel(
    const float* __restrict__ z,
    const float* __restrict__ w_w1, const float* __restrict__ w_b1,
    const float* __restrict__ w_g,  const float* __restrict__ w_beta,
    const float* __restrict__ w_w2, const float* __restrict__ w_b2,
    const float* __restrict__ b_w1, const float* __restrict__ b_b1,
    const float* __restrict__ b_g,  const float* __restrict__ b_beta,
    const float* __restrict__ b_w2, const float* __restrict__ b_b2,
    float* __restrict__ wT,    // [B][CH_in][CH_out]
    float* __restrict__ bias)  // [B][CH]
{
  const int b   = blockIdx.x;
  const int tid = threadIdx.x;

  __shared__ float zs[INS];
  __shared__ float hraw[2][HID];
  __shared__ float hn[2][HID];

  if (tid < INS) zs[tid] = z[b * INS + tid];
  __syncthreads();

  if (tid < 2 * HID) {
    const int grp = tid >> 5;          // 0 = weight-MLP, 1 = bias-MLP
    const int j   = tid & 31;
    const float* w1 = grp ? b_w1 : w_w1;
    const float* b1 = grp ? b_b1 : w_b1;
    hraw[grp][j] = w1[j*3+0]*zs[0] + w1[j*3+1]*zs[1] + w1[j*3+2]*zs[2] + b1[j];
  }
  __syncthreads();

  if (tid < 2 * HID) {
    const int grp = tid >> 5;
    const int j   = tid & 31;
    float mu = 0.f;
    #pragma unroll
    for (int k = 0; k < HID; ++k) mu += hraw[grp][k];
    mu *= (1.0f / HID);
    float var = 0.f;
    #pragma unroll
    for (int k = 0; k < HID; ++k) { float d = hraw[grp][k] - mu; var += d * d; }
    var *= (1.0f / HID);
    const float r  = rsqrtf(var + 1e-5f);
    const float* g  = grp ? b_g    : w_g;
    const float* be = grp ? b_beta : w_beta;
    const float v = (hraw[grp][j] - mu) * r * g[j] + be[j];
    hn[grp][j] = fmaxf(v, 0.f);
  }
  __syncthreads();

  for (int m = tid; m < CH * CH; m += 256) {
    const float* row = w_w2 + m * HID;
    float acc = w_b2[m];
    #pragma unroll
    for (int i = 0; i < HID; ++i) acc += hn[0][i] * row[i];
    // m = o*64 + i  ->  wT[b][i][o]
    wT[(size_t)b * CH * CH + (m & 63) * CH + (m >> 6)] = acc;
  }

  if (tid < CH) {
    const float* row = b_w2 + tid * HID;
    float acc = b_b2[tid];
    #pragma unroll
    for (int i = 0; i < HID; ++i) acc += hn[1][i] * row[i];
    bias[b * CH + tid] = acc;
  }
}

// ---------------------------------------------------------------------------
// Kernel 2: per-batch 64x64 matrix applied to x[b][64][T].
// Block = 512 threads = 8 waves; one (b, 256-t tile). x tile [64][256] (64KB)
// AND the 64x64 weight matrix (16KB) both staged in LDS -> inner loop is
// PURE ds_read + v_fmac (no SMEM/DS lgkmcnt mixing -> compiler emits counted
// lgkmcnt, pipelined). Wave w owns 8 outputs; lane owns 4 consecutive t.
// Per i-step per wave: 1 x ds_read_b128 + 2 broadcast w ds_read_b128
// (~36 DS cyc) + 64 v_fmac (128 cyc). acc = 8 float4 = 32 VGPR -> total ~64
// VGPR; LDS 80KB -> 2 blocks/CU = 16 waves/CU = 4 waves/SIMD.
// ---------------------------------------------------------------------------
__global__ __launch_bounds__(512, 4) void conv1x1_kernel(
    const float* __restrict__ x,
    const float* __restrict__ wT,
    const float* __restrict__ bias,
    float* __restrict__ out)
{
  const int b   = blockIdx.y;
  const int tbi = blockIdx.x;
  const int tid = threadIdx.x;

  __shared__ float4 xs[CH * (TB / 4)];   // [i][c]  64 KB
  __shared__ float4 ws[CH * (CH / 4)];   // [i][o/4] 16 KB

  // ---- stage x tile: 4096 float4s, 512 threads x 8, coalesced ----
  const float* xbase = x + (size_t)b * CH * T_LEN + tbi * TB;
  #pragma unroll
  for (int k = 0; k < 8; ++k) {
    const int f = tid + k * 512;
    const int i = f >> 6;          // row
    const int c = f & 63;          // float4 col
    xs[f] = *(const float4*)(xbase + (size_t)i * T_LEN + c * 4);
  }
  // ---- stage weights: 1024 float4s, 512 threads x 2 ----
  const float4* wsrc = (const float4*)(wT + (size_t)b * CH * CH);
  #pragma unroll
  for (int k = 0; k < 2; ++k) ws[tid + k * 512] = wsrc[tid + k * 512];
  __syncthreads();

  const int lane = tid & 63;
  const int wid  = __builtin_amdgcn_readfirstlane(tid >> 6);  // wave 0..7 -> o = 8*wid..

  float4 acc[8];
  #pragma unroll
  for (int q = 0; q < 8; ++q) acc[q] = make_float4(0.f, 0.f, 0.f, 0.f);

  #pragma unroll 8
  for (int i = 0; i < CH; ++i) {
    const float4 xv = xs[i * 64 + lane];
    const float4 w0 = ws[i * 16 + wid * 2 + 0];   // broadcast (same addr all lanes)
    const float4 w1 = ws[i * 16 + wid * 2 + 1];
    acc[0].x += w0.x * xv.x; acc[0].y += w0.x * xv.y; acc[0].z += w0.x * xv.z; acc[0].w += w0.x * xv.w;
    acc[1].x += w0.y * xv.x; acc[1].y += w0.y * xv.y; acc[1].z += w0.y * xv.z; acc[1].w += w0.y * xv.w;
    acc[2].x += w0.z * xv.x; acc[2].y += w0.z * xv.y; acc[2].z += w0.z * xv.z; acc[2].w += w0.z * xv.w;
    acc[3].x += w0.w * xv.x; acc[3].y += w0.w * xv.y; acc[3].z += w0.w * xv.z; acc[3].w += w0.w * xv.w;
    acc[4].x += w1.x * xv.x; acc[4].y += w1.x * xv.y; acc[4].z += w1.x * xv.z; acc[4].w += w1.x * xv.w;
    acc[5].x += w1.y * xv.x; acc[5].y += w1.y * xv.y; acc[5].z += w1.y * xv.z; acc[5].w += w1.y * xv.w;
    acc[6].x += w1.z * xv.x; acc[6].y += w1.z * xv.y; acc[6].z += w1.z * xv.z; acc[6].w += w1.z * xv.w;
    acc[7].x += w1.w * xv.x; acc[7].y += w1.w * xv.y; acc[7].z += w1.w * xv.z; acc[7].w += w1.w * xv.w;
  }

  // epilogue: bias from global (outside the hot loop; one vmcnt wait)
  const float4 bv0 = *(const float4*)(bias + b * CH + wid * 8);
  const float4 bv1 = *(const float4*)(bias + b * CH + wid * 8 + 4);
  float* op = out + ((size_t)b * CH + wid * 8) * T_LEN + tbi * TB + lane * 4;

  const float bb[8] = {bv0.x, bv0.y, bv0.z, bv0.w, bv1.x, bv1.y, bv1.z, bv1.w};
  #pragma unroll
  for (int m = 0; m < 8; ++m) {
    float4 r;
    r.x = acc[m].x + bb[m]; r.y = acc[m].y + bb[m];
    r.z = acc[m].z + bb[m]; r.w = acc[m].w + bb[m];
    *(float4*)(op + (size_t)m * T_LEN) = r;
  }
}

extern "C" void kernel_launch(void* const* d_in, const int* in_sizes, int n_in,
                              void* d_out, int out_size, void* d_ws, size_t ws_size,
                              hipStream_t stream) {
  const float* x      = (const float*)d_in[0];
  const float* z      = (const float*)d_in[1];
  const float* w_w1   = (const float*)d_in[2];
  const float* w_b1   = (const float*)d_in[3];
  const float* w_g    = (const float*)d_in[4];
  const float* w_beta = (const float*)d_in[5];
  const float* w_w2   = (const float*)d_in[6];
  const float* w_b2   = (const float*)d_in[7];
  const float* b_w1   = (const float*)d_in[8];
  const float* b_b1   = (const float*)d_in[9];
  const float* b_g    = (const float*)d_in[10];
  const float* b_beta = (const float*)d_in[11];
  const float* b_w2   = (const float*)d_in[12];
  const float* b_b2   = (const float*)d_in[13];

  float* out  = (float*)d_out;
  float* wT   = (float*)d_ws;                      // 128*64*64 floats = 2 MB
  float* bias = wT + (size_t)B_SZ * CH * CH;       // 128*64 floats

  hyper_mlp_kernel<<<B_SZ, 256, 0, stream>>>(
      z, w_w1, w_b1, w_g, w_beta, w_w2, w_b2,
      b_w1, b_b1, b_g, b_beta, b_w2, b_b2, wT, bias);

  dim3 grid(T_LEN / TB, B_SZ);
  conv1x1_kernel<<<grid, 512, 0, stream>>>(x, wT, bias, out);
}

// Round 5
// 89.546 us; speedup vs baseline: 1.0626x; 1.0123x over previous
//
#include <hip/hip_runtime.h>

#define B_SZ  128
#define CH    64
#define T_LEN 4096
#define HID   32
#define INS   3
#define TB    256   // t-columns per block

// ---------------------------------------------------------------------------
// Kernel 1: hypernetwork MLPs. One block per batch sample.
// Writes weight TRANSPOSED as wT[b][i][o].
// ---------------------------------------------------------------------------
__global__ __launch_bounds__(256) void hyper_mlp_kernel(
    const float* __restrict__ z,
    const float* __restrict__ w_w1, const float* __restrict__ w_b1,
    const float* __restrict__ w_g,  const float* __restrict__ w_beta,
    const float* __restrict__ w_w2, const float* __restrict__ w_b2,
    const float* __restrict__ b_w1, const float* __restrict__ b_b1,
    const float* __restrict__ b_g,  const float* __restrict__ b_beta,
    const float* __restrict__ b_w2, const float* __restrict__ b_b2,
    float* __restrict__ wT,    // [B][CH_in][CH_out]
    float* __restrict__ bias)  // [B][CH]
{
  const int b   = blockIdx.x;
  const int tid = threadIdx.x;

  __shared__ float zs[INS];
  __shared__ float hraw[2][HID];
  __shared__ float hn[2][HID];

  if (tid < INS) zs[tid] = z[b * INS + tid];
  __syncthreads();

  if (tid < 2 * HID) {
    const int grp = tid >> 5;          // 0 = weight-MLP, 1 = bias-MLP
    const int j   = tid & 31;
    const float* w1 = grp ? b_w1 : w_w1;
    const float* b1 = grp ? b_b1 : w_b1;
    hraw[grp][j] = w1[j*3+0]*zs[0] + w1[j*3+1]*zs[1] + w1[j*3+2]*zs[2] + b1[j];
  }
  __syncthreads();

  if (tid < 2 * HID) {
    const int grp = tid >> 5;
    const int j   = tid & 31;
    float mu = 0.f;
    #pragma unroll
    for (int k = 0; k < HID; ++k) mu += hraw[grp][k];
    mu *= (1.0f / HID);
    float var = 0.f;
    #pragma unroll
    for (int k = 0; k < HID; ++k) { float d = hraw[grp][k] - mu; var += d * d; }
    var *= (1.0f / HID);
    const float r  = rsqrtf(var + 1e-5f);
    const float* g  = grp ? b_g    : w_g;
    const float* be = grp ? b_beta : w_beta;
    const float v = (hraw[grp][j] - mu) * r * g[j] + be[j];
    hn[grp][j] = fmaxf(v, 0.f);
  }
  __syncthreads();

  for (int m = tid; m < CH * CH; m += 256) {
    const float* row = w_w2 + m * HID;
    float acc = w_b2[m];
    #pragma unroll
    for (int i = 0; i < HID; ++i) acc += hn[0][i] * row[i];
    // m = o*64 + i  ->  wT[b][i][o]
    wT[(size_t)b * CH * CH + (m & 63) * CH + (m >> 6)] = acc;
  }

  if (tid < CH) {
    const float* row = b_w2 + tid * HID;
    float acc = b_b2[tid];
    #pragma unroll
    for (int i = 0; i < HID; ++i) acc += hn[1][i] * row[i];
    bias[b * CH + tid] = acc;
  }
}

// ---------------------------------------------------------------------------
// Kernel 2: per-batch 64x64 matrix applied to x[b][64][T].
// NO LDS, NO barriers. Block = 512 threads = 8 waves on one (b, 256-t tile).
// Wave w owns outputs 8w..8w+7; weights are read through a readfirstlane'd
// (wave-uniform) pointer -> s_load_dwordx4 (SMEM only in lgkmcnt: in-order,
// pipelines cleanly; no DS mixing). Each lane reads its 4 t-columns straight
// from global (vmcnt-pipelined, unroll 4); the 8x intra-block reuse of each
// 1 KB x line is served by L1 since the 8 waves sweep i nearly in lockstep.
// Loads stream continuously -> full overlap with FMA, no phase serialization.
// acc = 8 float4 = 32 VGPR; ~60 VGPR total -> 8 waves/SIMD.
// ---------------------------------------------------------------------------
__global__ __launch_bounds__(512, 8) void conv1x1_kernel(
    const float* __restrict__ x,
    const float* __restrict__ wT,
    const float* __restrict__ bias,
    float* __restrict__ out)
{
  const int b    = blockIdx.y;
  const int tbi  = blockIdx.x;
  const int tid  = threadIdx.x;
  const int lane = tid & 63;
  const int wid  = __builtin_amdgcn_readfirstlane(tid >> 6);  // wave's o-group

  // wave-uniform weight pointer: wT[b][i][8*wid .. 8*wid+7], stride 16 float4/i
  const float4* wp = (const float4*)(wT + (size_t)b * CH * CH) + wid * 2;
  const float*  xp = x + (size_t)b * CH * T_LEN + tbi * TB + lane * 4;

  float4 acc[8];
  #pragma unroll
  for (int q = 0; q < 8; ++q) acc[q] = make_float4(0.f, 0.f, 0.f, 0.f);

  #pragma unroll 4
  for (int i = 0; i < CH; ++i) {
    const float4 xv = *(const float4*)(xp + (size_t)i * T_LEN);
    const float4 w0 = wp[i * 16 + 0];   // s_load (uniform)
    const float4 w1 = wp[i * 16 + 1];
    acc[0].x += w0.x * xv.x; acc[0].y += w0.x * xv.y; acc[0].z += w0.x * xv.z; acc[0].w += w0.x * xv.w;
    acc[1].x += w0.y * xv.x; acc[1].y += w0.y * xv.y; acc[1].z += w0.y * xv.z; acc[1].w += w0.y * xv.w;
    acc[2].x += w0.z * xv.x; acc[2].y += w0.z * xv.y; acc[2].z += w0.z * xv.z; acc[2].w += w0.z * xv.w;
    acc[3].x += w0.w * xv.x; acc[3].y += w0.w * xv.y; acc[3].z += w0.w * xv.z; acc[3].w += w0.w * xv.w;
    acc[4].x += w1.x * xv.x; acc[4].y += w1.x * xv.y; acc[4].z += w1.x * xv.z; acc[4].w += w1.x * xv.w;
    acc[5].x += w1.y * xv.x; acc[5].y += w1.y * xv.y; acc[5].z += w1.y * xv.z; acc[5].w += w1.y * xv.w;
    acc[6].x += w1.z * xv.x; acc[6].y += w1.z * xv.y; acc[6].z += w1.z * xv.z; acc[6].w += w1.z * xv.w;
    acc[7].x += w1.w * xv.x; acc[7].y += w1.w * xv.y; acc[7].z += w1.w * xv.z; acc[7].w += w1.w * xv.w;
  }

  const float4 bv0 = *(const float4*)(bias + b * CH + wid * 8);
  const float4 bv1 = *(const float4*)(bias + b * CH + wid * 8 + 4);
  float* op = out + ((size_t)b * CH + wid * 8) * T_LEN + tbi * TB + lane * 4;

  const float bb[8] = {bv0.x, bv0.y, bv0.z, bv0.w, bv1.x, bv1.y, bv1.z, bv1.w};
  #pragma unroll
  for (int m = 0; m < 8; ++m) {
    float4 r;
    r.x = acc[m].x + bb[m]; r.y = acc[m].y + bb[m];
    r.z = acc[m].z + bb[m]; r.w = acc[m].w + bb[m];
    *(float4*)(op + (size_t)m * T_LEN) = r;
  }
}

extern "C" void kernel_launch(void* const* d_in, const int* in_sizes, int n_in,
                              void* d_out, int out_size, void* d_ws, size_t ws_size,
                              hipStream_t stream) {
  const float* x      = (const float*)d_in[0];
  const float* z      = (const float*)d_in[1];
  const float* w_w1   = (const float*)d_in[2];
  const float* w_b1   = (const float*)d_in[3];
  const float* w_g    = (const float*)d_in[4];
  const float* w_beta = (const float*)d_in[5];
  const float* w_w2   = (const float*)d_in[6];
  const float* w_b2   = (const float*)d_in[7];
  const float* b_w1   = (const float*)d_in[8];
  const float* b_b1   = (const float*)d_in[9];
  const float* b_g    = (const float*)d_in[10];
  const float* b_beta = (const float*)d_in[11];
  const float* b_w2   = (const float*)d_in[12];
  const float* b_b2   = (const float*)d_in[13];

  float* out  = (float*)d_out;
  float* wT   = (float*)d_ws;                      // 128*64*64 floats = 2 MB
  float* bias = wT + (size_t)B_SZ * CH * CH;       // 128*64 floats

  hyper_mlp_kernel<<<B_SZ, 256, 0, stream>>>(
      z, w_w1, w_b1, w_g, w_beta, w_w2, w_b2,
      b_w1, b_b1, b_g, b_beta, b_w2, b_b2, wT, bias);

  dim3 grid(T_LEN / TB, B_SZ);
  conv1x1_kernel<<<grid, 512, 0, stream>>>(x, wT, bias, out);
}